// Round 4
// baseline (18676.523 us; speedup 1.0000x reference)
//
#include <hip/hip_runtime.h>
#include <math.h>

#define BB 32
#define TT 128
#define EE 512
#define UU 1024
#define GG 4096   // 4*UU, row stride of weight matrices

typedef float f32x4 __attribute__((ext_vector_type(4)));

__device__ __forceinline__ float sigf(float x){ return 1.0f/(1.0f + expf(-x)); }

// ---------------- embedding gather into xT[t][e][b] ----------------
__global__ void gather_k(const int* __restrict__ tokens, const float* __restrict__ emb,
                         float* __restrict__ xT){
  int idx = blockIdx.x*256 + threadIdx.x;           // total T*E*B = 2^21
  int b = idx & 31, e = (idx>>5)&511, t = idx>>14;
  int tok = tokens[b*TT + t];
  xT[idx] = emb[(size_t)tok*EE + e];
}

// Thread mapping (both step kernels), 512 threads:
//   kq = tid&15   : 16-way k-split (in-wave -> shfl butterfly reduction)
//   cq = (tid>>4)&3 : gate index (i,f,g,o)
//   bq = tid>>6   : wave index = batch quad (4 rows of B=32)
// Block owns 4 u-columns: ub = lb*4 (lb = XCD-swizzled block id), i.e. 16
// weight cols (4 gates x 4). Weight loads: 16B per lane, 64 distinct/wave.
// XCD swizzle: dispatch d -> XCD d%8; lb=(d&7)*32+(d>>3) gives each XCD a
// contiguous 128-col panel so every 128B weight line is consumed in one L2.

// ---------------- step kernel 1: z0 = x@W0 + h@U0 + b0 -> h0 ----------------
__global__ __launch_bounds__(512) void lstm_k2(
    const float* __restrict__ xTt,   // [512][32] t-slice
    const float* __restrict__ W0,    // [512][4096]
    const float* __restrict__ U0,    // [1024][4096]
    const float* __restrict__ b0,
    const float* __restrict__ hin,   // [1024][32] prev h
    const float* __restrict__ cT,    // [1024][32] prev c
    float* __restrict__ h0T)         // [1024][32]
{
  __shared__ float zb[16*36];
  int tid = threadIdx.x;
  int lb  = ((blockIdx.x & 7) << 5) | (blockIdx.x >> 3);
  int ub  = lb << 2;
  int kq = tid & 15, cq = (tid >> 4) & 3, bq = tid >> 6;
  int bq4 = bq << 2;
  int col = cq * UU + ub;
  float acc[4][4] = {{0.f,0.f,0.f,0.f},{0.f,0.f,0.f,0.f},{0.f,0.f,0.f,0.f},{0.f,0.f,0.f,0.f}};

  // ---- x @ W0 (K = 512) ----
  {
    const float* wp = W0 + col;
    #pragma unroll 4
    for (int j = 0; j < 32; ++j) {
      int k = (j << 4) + kq;
      f32x4 w  = *(const f32x4*)(wp + (size_t)k * GG);
      f32x4 xv = *(const f32x4*)(xTt + (k << 5) + bq4);
      #pragma unroll
      for (int bi = 0; bi < 4; ++bi)
        #pragma unroll
        for (int ci = 0; ci < 4; ++ci)
          acc[bi][ci] += xv[bi] * w[ci];
    }
  }
  __syncthreads();                    // wave convergence (L1 weight reuse)
  // ---- h @ U0 (K = 1024) ----
  {
    const float* wp = U0 + col;
    for (int jb = 0; jb < 64; jb += 32) {
      #pragma unroll 4
      for (int j = jb; j < jb + 32; ++j) {
        int k = (j << 4) + kq;
        f32x4 w  = *(const f32x4*)(wp + (size_t)k * GG);
        f32x4 hv = *(const f32x4*)(hin + (k << 5) + bq4);
        #pragma unroll
        for (int bi = 0; bi < 4; ++bi)
          #pragma unroll
          for (int ci = 0; ci < 4; ++ci)
            acc[bi][ci] += hv[bi] * w[ci];
      }
      __syncthreads();
    }
  }
  // ---- kq butterfly reduction (in-wave, 16-lane groups) ----
  #pragma unroll
  for (int bi = 0; bi < 4; ++bi)
    #pragma unroll
    for (int ci = 0; ci < 4; ++ci) {
      float a = acc[bi][ci];
      a += __shfl_xor(a, 1); a += __shfl_xor(a, 2);
      a += __shfl_xor(a, 4); a += __shfl_xor(a, 8);
      acc[bi][ci] = a;
    }
  // ---- deposit z columns to LDS (lane kq==ci extracts column ci) ----
  #pragma unroll
  for (int ci = 0; ci < 4; ++ci)
    if (kq == ci) {
      f32x4 z = {acc[0][ci], acc[1][ci], acc[2][ci], acc[3][ci]};
      *(f32x4*)&zb[(cq*4 + ci)*36 + bq4] = z;
    }
  __syncthreads();
  // ---- cell-0 gates on 128 parallel lanes ----
  if (tid < 128) {
    int b = tid & 31, uj = tid >> 5;
    int u = ub + uj;
    float zi = zb[(0*4 + uj)*36 + b] + b0[u];
    float zf = zb[(1*4 + uj)*36 + b] + b0[UU + u];
    float zg = zb[(2*4 + uj)*36 + b] + b0[2*UU + u];
    float zo = zb[(3*4 + uj)*36 + b] + b0[3*UU + u];
    float c0 = sigf(zf) * cT[(u<<5) + b] + sigf(zi) * tanhf(zg);
    h0T[(u<<5) + b] = sigf(zo) * tanhf(c0);   // cell-0 c discarded (reference quirk)
  }
}

// ---------------- step kernel 2: z1 = h0@W1 + hprev@U1 + b1 -> h,c ----------------
__global__ __launch_bounds__(512) void lstm_k3(
    const float* __restrict__ h0T,   // [1024][32]
    const float* __restrict__ W1,    // [1024][4096]
    const float* __restrict__ U1,    // [1024][4096]
    const float* __restrict__ b1,
    const float* __restrict__ hin,   // [1024][32] prev h (read-only; out is hout)
    float* __restrict__ hout,        // [1024][32]
    float* __restrict__ cT)          // [1024][32] in-place (own cols only)
{
  __shared__ float zb[16*36];
  int tid = threadIdx.x;
  int lb  = ((blockIdx.x & 7) << 5) | (blockIdx.x >> 3);
  int ub  = lb << 2;
  int kq = tid & 15, cq = (tid >> 4) & 3, bq = tid >> 6;
  int bq4 = bq << 2;
  int col = cq * UU + ub;
  float acc[4][4] = {{0.f,0.f,0.f,0.f},{0.f,0.f,0.f,0.f},{0.f,0.f,0.f,0.f},{0.f,0.f,0.f,0.f}};

  const float* w1p = W1 + col;
  const float* u1p = U1 + col;
  for (int jb = 0; jb < 64; jb += 32) {
    #pragma unroll 4
    for (int j = jb; j < jb + 32; ++j) {
      int k = (j << 4) + kq;
      f32x4 wa = *(const f32x4*)(w1p + (size_t)k * GG);
      f32x4 wb = *(const f32x4*)(u1p + (size_t)k * GG);
      f32x4 ha = *(const f32x4*)(h0T + (k << 5) + bq4);
      f32x4 hb = *(const f32x4*)(hin + (k << 5) + bq4);
      #pragma unroll
      for (int bi = 0; bi < 4; ++bi)
        #pragma unroll
        for (int ci = 0; ci < 4; ++ci)
          acc[bi][ci] += ha[bi] * wa[ci] + hb[bi] * wb[ci];
    }
    __syncthreads();
  }
  #pragma unroll
  for (int bi = 0; bi < 4; ++bi)
    #pragma unroll
    for (int ci = 0; ci < 4; ++ci) {
      float a = acc[bi][ci];
      a += __shfl_xor(a, 1); a += __shfl_xor(a, 2);
      a += __shfl_xor(a, 4); a += __shfl_xor(a, 8);
      acc[bi][ci] = a;
    }
  #pragma unroll
  for (int ci = 0; ci < 4; ++ci)
    if (kq == ci) {
      f32x4 z = {acc[0][ci], acc[1][ci], acc[2][ci], acc[3][ci]};
      *(f32x4*)&zb[(cq*4 + ci)*36 + bq4] = z;
    }
  __syncthreads();
  if (tid < 128) {
    int b = tid & 31, uj = tid >> 5;
    int u = ub + uj;
    float zi = zb[(0*4 + uj)*36 + b] + b1[u];
    float zf = zb[(1*4 + uj)*36 + b] + b1[UU + u];
    float zg = zb[(2*4 + uj)*36 + b] + b1[2*UU + u];
    float zo = zb[(3*4 + uj)*36 + b] + b1[3*UU + u];
    float cold = cT[(u<<5) + b];
    float cn = sigf(zf) * cold + sigf(zi) * tanhf(zg);
    float hn = sigf(zo) * tanhf(cn);
    hout[(u<<5) + b] = hn;
    cT[(u<<5) + b] = cn;
  }
}

// ---------------- final: out[b] = sigmoid(h_last . fc_w + fc_b) ----------------
__global__ __launch_bounds__(256) void lstm_out(const float* __restrict__ hT,
    const float* __restrict__ fcw, const float* __restrict__ fcb, float* __restrict__ out){
  __shared__ float r[256];
  int b = blockIdx.x, tid = threadIdx.x;
  float s = 0.f;
  for (int u = tid; u < UU; u += 256) s += hT[(u<<5) + b] * fcw[u];
  r[tid] = s; __syncthreads();
  for (int st = 128; st > 0; st >>= 1){ if (tid < st) r[tid] += r[tid+st]; __syncthreads(); }
  if (tid == 0) out[b] = 1.0f/(1.0f + expf(-(r[0] + fcb[0])));
}

extern "C" void kernel_launch(void* const* d_in, const int* in_sizes, int n_in,
                              void* d_out, int out_size, void* d_ws, size_t ws_size,
                              hipStream_t stream) {
  const int*   tokens = (const int*)  d_in[0];
  const float* emb    = (const float*)d_in[1];
  const float* W0     = (const float*)d_in[2];
  const float* U0     = (const float*)d_in[3];
  const float* b0     = (const float*)d_in[4];
  const float* W1     = (const float*)d_in[5];   // dict order: W1 before U1
  const float* U1     = (const float*)d_in[6];
  const float* b1     = (const float*)d_in[7];
  const float* fcw    = (const float*)d_in[8];
  const float* fcb    = (const float*)d_in[9];

  float* ws  = (float*)d_ws;
  float* xT  = ws;                         // 128*512*32 floats (8 MB)
  float* hA  = xT  + (size_t)TT*EE*BB;     // [1024][32]
  float* cT  = hA  + 32768;
  float* hB  = cT  + 32768;
  float* h0T = hB  + 32768;

  // zero initial h (hA) and c (adjacent) — ws is re-poisoned before every launch
  hipMemsetAsync(hA, 0, (size_t)2*32768*sizeof(float), stream);

  gather_k<<<8192, 256, 0, stream>>>(tokens, emb, xT);

  for (int t = 0; t < TT; ++t) {
    const float* hin  = (t & 1) ? hB : hA;
    float*       hout = (t & 1) ? hA : hB;
    lstm_k2<<<256, 512, 0, stream>>>(xT + (size_t)t*EE*BB, W0, U0, b0, hin, cT, h0T);
    lstm_k3<<<256, 512, 0, stream>>>(h0T, W1, U1, b1, hin, hout, cT);
  }
  // T=128 even -> last write was to hA
  lstm_out<<<32, 256, 0, stream>>>(hA, fcw, fcb, (float*)d_out);
}